// Round 2
// baseline (1554.611 us; speedup 1.0000x reference)
//
#include <hip/hip_runtime.h>
#include <hip/hip_bf16.h>
#include <hip/hip_fp16.h>

using bf16 = __hip_bfloat16;

#define PT 404      // t-pitch (>= 401, multiple of 4)
#define LSEQ 401
#define DM 192
#define DI 384
#define DS 16
#define NB 32

// ---- fp32 weights region layout (element offsets, computed from fixed shapes) ----
#define O_IMGS   0
#define O_PW     51200
#define O_PB     51968
#define O_CLS    52160
#define O_POS    52352
#define O_NORMW  129344
#define O_INW    130112
#define O_CONVW  719936
#define O_CONVB  726080
#define O_XPW    727616
#define O_DTW    795200
#define O_DTB    813632
#define O_ALOG   815168
#define O_DS     839744
#define O_OUTW   841280
#define O_NORMF  1136192
#define O_HEADW  1136384
#define O_HEADB  1328384
#define WTOT     1329408   // padded to multiple of 64

__constant__ int g_sz[18] = {51200, 768, 192, 192, 76992, 768, 589824, 6144, 1536,
                             67584, 18432, 1536, 24576, 1536, 294912, 192, 192000, 1000};
__constant__ int g_off[18] = {O_IMGS, O_PW, O_PB, O_CLS, O_POS, O_NORMW, O_INW, O_CONVW,
                              O_CONVB, O_XPW, O_DTW, O_DTB, O_ALOG, O_DS, O_OUTW,
                              O_NORMF, O_HEADW, O_HEADB};

struct SrcPtrs { const void* p[18]; };

static __device__ __forceinline__ int probe_flag(const unsigned short* probe) {
    unsigned short u0 = probe[0];
    if (u0 == 0x3F80u) return 0;  // bf16 (1.0)
    if (u0 == 0x3C00u) return 2;  // fp16 (1.0)
    return 1;                     // fp32 (low half of 1.0f == 0x0000)
}

// ---------------- ingest: convert all inputs to fp32 in ws ----------------
__global__ void convert_kernel(SrcPtrs sp, const unsigned short* __restrict__ probe,
                               float* __restrict__ dst) {
    int flag = probe_flag(probe);
    int which = blockIdx.y;
    int n = g_sz[which];
    const void* src = sp.p[which];
    float* d = dst + g_off[which];
    for (int i = blockIdx.x * blockDim.x + threadIdx.x; i < n; i += gridDim.x * blockDim.x) {
        float v;
        if (flag == 0)      v = __bfloat162float(((const bf16*)src)[i]);
        else if (flag == 1) v = ((const float*)src)[i];
        else                v = __half2float(((const __half*)src)[i]);
        d[i] = v;
    }
}

// ---------------- embed: xT[b][c][t] = patch/cls + pos ----------------
__global__ void embed_kernel(const float* __restrict__ W, float* __restrict__ xT) {
    const float* imgs = W + O_IMGS;
    const float* pw   = W + O_PW;
    const float* pb   = W + O_PB;
    const float* cls  = W + O_CLS;
    const float* pos  = W + O_POS;
    int b = blockIdx.z, c = blockIdx.y;
    int t = blockIdx.x * 64 + threadIdx.x;
    if (t > 400) return;
    float v;
    if (t < 400) {
        float s0 = imgs[b * 1600 + t * 4 + 0];
        float s1 = imgs[b * 1600 + t * 4 + 1];
        float s2 = imgs[b * 1600 + t * 4 + 2];
        float s3 = imgs[b * 1600 + t * 4 + 3];
        v = s0 * pw[0 * DM + c] + s1 * pw[1 * DM + c] +
            s2 * pw[2 * DM + c] + s3 * pw[3 * DM + c] +
            pb[c] + pos[t * DM + c];
    } else {
        v = cls[c] + pos[400 * DM + c];
    }
    xT[((long)b * DM + c) * PT + t] = v;
}

// ---------------- residual + rmsnorm (t-major) ----------------
__global__ __launch_bounds__(256) void resnorm_kernel(
    const float* __restrict__ xT, float* __restrict__ resT, float* __restrict__ hT,
    const float* __restrict__ w, int first) {
    int b = blockIdx.y;
    int tsub = threadIdx.x & 63;
    int cg = threadIdx.x >> 6;   // 0..3, 48 channels each
    int t = blockIdx.x * 64 + tsub;
    bool tok = (t < LSEQ);
    __shared__ float part[4][64];
    __shared__ float invs[64];
    float vals[48];
    float ss = 0.f;
    long base = ((long)b * DM + cg * 48) * PT + t;
#pragma unroll
    for (int i = 0; i < 48; ++i) {
        float v = 0.f;
        if (tok) {
            long off = base + (long)i * PT;
            v = xT[off];
            if (!first) v += resT[off];
            resT[off] = v;
        }
        vals[i] = v;
        ss = fmaf(v, v, ss);
    }
    part[cg][tsub] = ss;
    __syncthreads();
    if (threadIdx.x < 64) {
        float tot = part[0][threadIdx.x] + part[1][threadIdx.x] +
                    part[2][threadIdx.x] + part[3][threadIdx.x];
        invs[threadIdx.x] = rsqrtf(tot * (1.f / DM) + 1e-5f);
    }
    __syncthreads();
    float iv = invs[tsub];
#pragma unroll
    for (int i = 0; i < 48; ++i) {
        if (tok) {
            int c = cg * 48 + i;
            hT[base + (long)i * PT] = vals[i] * iv * w[c];
        }
    }
}

// ---------------- generic batched GEMM: C[b][n][t] = act(sum_k W[k][n]*A[b][k][t] + bias) ----
// BN=64, BT=128, BK=16, TN=4, TT=8, 256 threads. ACT: 0=none, 1=softplus(+bias)
template <int ACT>
__global__ __launch_bounds__(256) void gemm_wt(
    const float* __restrict__ A, long strideAb,
    const float* __restrict__ W, const float* __restrict__ bias,
    float* __restrict__ C, long strideCb, int N, int K) {
    constexpr int BN = 64, BT = 128, BK = 16;
    __shared__ float As[BK][BT + 4];
    __shared__ float Ws[BK][BN + 4];
    int b = blockIdx.z;
    int t0 = blockIdx.x * BT;
    int n0 = blockIdx.y * BN;
    A += (long)b * strideAb;
    C += (long)b * strideCb;
    int tid = threadIdx.x;
    int tt = tid & 15;   // t-group: 8 t's each
    int tn = tid >> 4;   // n-group: 4 n's each
    float acc[4][8] = {};
    for (int k0 = 0; k0 < K; k0 += BK) {
        // A tile: 16 x 128
        {
            int r = tid >> 5;            // 0..7
            int c4 = (tid & 31) * 4;     // 0..124
#pragma unroll
            for (int it = 0; it < 2; ++it) {
                int kk = r + it * 8;
                int k = k0 + kk;
                float4 v = make_float4(0.f, 0.f, 0.f, 0.f);
                if (k < K) v = *(const float4*)(A + (long)k * PT + t0 + c4);
                *(float4*)&As[kk][c4] = v;
            }
        }
        // W tile: 16 x 64
        {
            int r = tid >> 4;            // kk
            int cc = (tid & 15) * 4;
            float4 wv = make_float4(0.f, 0.f, 0.f, 0.f);
            int k = k0 + r;
            if (k < K) {
                if (n0 + cc + 3 < N) {
                    wv = *(const float4*)(W + (long)k * N + n0 + cc);
                } else {
                    float* wp = (float*)&wv;
#pragma unroll
                    for (int i = 0; i < 4; ++i) {
                        int n = n0 + cc + i;
                        if (n < N) wp[i] = W[(long)k * N + n];
                    }
                }
            }
            *(float4*)&Ws[r][cc] = wv;
        }
        __syncthreads();
#pragma unroll
        for (int kk = 0; kk < BK; ++kk) {
            float4 wv = *(const float4*)&Ws[kk][tn * 4];
            float4 a0 = *(const float4*)&As[kk][tt * 8];
            float4 a1 = *(const float4*)&As[kk][tt * 8 + 4];
            float av[8] = {a0.x, a0.y, a0.z, a0.w, a1.x, a1.y, a1.z, a1.w};
            float wn[4] = {wv.x, wv.y, wv.z, wv.w};
#pragma unroll
            for (int i = 0; i < 4; ++i)
#pragma unroll
                for (int j = 0; j < 8; ++j)
                    acc[i][j] = fmaf(wn[i], av[j], acc[i][j]);
        }
        __syncthreads();
    }
#pragma unroll
    for (int i = 0; i < 4; ++i) {
        int n = n0 + tn * 4 + i;
        if (n >= N) continue;
        float bv = 0.f;
        if (ACT == 1) bv = bias[n];
#pragma unroll
        for (int j = 0; j < 8; ++j) {
            int t = t0 + tt * 8 + j;
            if (t >= LSEQ) continue;
            float v = acc[i][j];
            if (ACT == 1) {
                v += bv;
                v = (v > 20.f) ? v : log1pf(__expf(v));
            }
            C[(long)n * PT + t] = v;
        }
    }
}

// ---------------- causal depthwise conv (width 4) + silu ----------------
__global__ void conv_silu_kernel(const float* __restrict__ xzT, const float* __restrict__ cw,
                                 const float* __restrict__ cb, float* __restrict__ ucT) {
    int b = blockIdx.z, d = blockIdx.y;
    int t = blockIdx.x * 256 + threadIdx.x;
    if (t >= LSEQ) return;
    const float* pu = xzT + ((long)b * (2 * DI) + d) * PT;
    float w0 = cw[d * 4 + 0], w1 = cw[d * 4 + 1];
    float w2 = cw[d * 4 + 2], w3 = cw[d * 4 + 3];
    float acc = cb[d] + w3 * pu[t];
    if (t >= 1) acc += w2 * pu[t - 1];
    if (t >= 2) acc += w1 * pu[t - 2];
    if (t >= 3) acc += w0 * pu[t - 3];
    float sv = acc / (1.f + __expf(-acc));   // silu
    ucT[((long)b * DI + d) * PT + t] = sv;
}

// ---------------- selective scan + D-term + z-gating ----------------
__global__ __launch_bounds__(256) void scan_kernel(
    const float* __restrict__ deltaT, const float* __restrict__ ucT,
    const float* __restrict__ dblT, const float* __restrict__ xzT,
    const float* __restrict__ Alog, const float* __restrict__ Dvec,
    float* __restrict__ ygT) {
    int b = blockIdx.y, dg = blockIdx.x, tid = threadIdx.x;
    int s = tid & 15, dl = tid >> 4;
    int d = dg * 16 + dl;
    float a = -__expf(Alog[d * DS + s]);
    float Dp = Dvec[d];
    const float* pd = deltaT + ((long)b * DI + d) * PT;
    const float* pu = ucT + ((long)b * DI + d) * PT;
    const float* pB = dblT + ((long)b * 44 + 12 + s) * PT;
    const float* pC = dblT + ((long)b * 44 + 28 + s) * PT;
    const float* pz = xzT + ((long)b * (2 * DI) + DI + d) * PT;
    float* py = ygT + ((long)b * DI + d) * PT;
    float h = 0.f;
    float4 d4 = *(const float4*)pd;
    float4 u4 = *(const float4*)pu;
    float4 B4 = *(const float4*)pB;
    float4 C4 = *(const float4*)pC;
    float4 z4 = *(const float4*)pz;
    for (int tc = 0; tc < 101; ++tc) {
        float4 nd4 = d4, nu4 = u4, nB4 = B4, nC4 = C4, nz4 = z4;
        if (tc < 100) {
            int nt = (tc + 1) * 4;
            nd4 = *(const float4*)(pd + nt);
            nu4 = *(const float4*)(pu + nt);
            nB4 = *(const float4*)(pB + nt);
            nC4 = *(const float4*)(pC + nt);
            nz4 = *(const float4*)(pz + nt);
        }
        float dv[4], uv[4], Bv[4], Cv[4], zv[4], yout[4];
        *(float4*)dv = d4; *(float4*)uv = u4; *(float4*)Bv = B4;
        *(float4*)Cv = C4; *(float4*)zv = z4;
#pragma unroll
        for (int j = 0; j < 4; ++j) {
            int t = tc * 4 + j;
            yout[j] = 0.f;
            if (t < LSEQ) {
                float dlt = dv[j];
                float da = __expf(dlt * a);
                h = fmaf(da, h, dlt * uv[j] * Bv[j]);
                float p = h * Cv[j];
                p += __shfl_xor(p, 1, 16);
                p += __shfl_xor(p, 2, 16);
                p += __shfl_xor(p, 4, 16);
                p += __shfl_xor(p, 8, 16);
                float y = fmaf(uv[j], Dp, p);
                float z = zv[j];
                yout[j] = y * (z / (1.f + __expf(-z)));
            }
        }
        if (s == 0) {
            int t = tc * 4;
            if (t + 3 < LSEQ) {
                *(float4*)(py + t) = make_float4(yout[0], yout[1], yout[2], yout[3]);
            } else {
#pragma unroll
                for (int j = 0; j < 4; ++j)
                    if (t + j < LSEQ) py[t + j] = yout[j];
            }
        }
        d4 = nd4; u4 = nu4; B4 = nB4; C4 = nC4; z4 = nz4;
    }
}

// ---------------- final norm at t=400 ----------------
__global__ void finalnorm_kernel(const float* __restrict__ xT, const float* __restrict__ resT,
                                 const float* __restrict__ w, float* __restrict__ v) {
    int b = blockIdx.x;
    int c = threadIdx.x;   // 256 threads
    __shared__ float sb[256];
    float val = 0.f;
    if (c < DM) {
        long off = ((long)b * DM + c) * PT + 400;
        val = xT[off] + resT[off];
    }
    sb[c] = val * val;
    __syncthreads();
    for (int o = 128; o > 0; o >>= 1) {
        if (c < o) sb[c] += sb[c + o];
        __syncthreads();
    }
    float inv = rsqrtf(sb[0] * (1.f / DM) + 1e-5f);
    if (c < DM) v[b * DM + c] = val * inv * w[c];
}

// ---------------- head: out[b][n] = v[b] . head_w[:,n] + head_b[n] ----------------
__global__ void head_kernel(const float* __restrict__ v, const float* __restrict__ hw,
                            const float* __restrict__ hb,
                            const unsigned short* __restrict__ probe, void* __restrict__ out) {
    int b = blockIdx.y;
    int n = blockIdx.x * 128 + threadIdx.x;
    __shared__ float vs[DM];
    for (int i = threadIdx.x; i < DM; i += 128) vs[i] = v[b * DM + i];
    __syncthreads();
    if (n < 1000) {
        float acc = hb[n];
#pragma unroll 4
        for (int c = 0; c < DM; ++c) acc = fmaf(vs[c], hw[c * 1000 + n], acc);
        int flag = probe_flag(probe);
        if (flag == 0)      ((bf16*)out)[b * 1000 + n] = (bf16)acc;
        else if (flag == 2) ((__half*)out)[b * 1000 + n] = __float2half(acc);
        else                ((float*)out)[b * 1000 + n] = acc;
    }
}

extern "C" void kernel_launch(void* const* d_in, const int* in_sizes, int n_in,
                              void* d_out, int out_size, void* d_ws, size_t ws_size,
                              hipStream_t stream) {
    float* ws = (float*)d_ws;
    float* Wr = ws;                      // fp32 weights region
    const long SZ_DM = (long)NB * DM * PT;        // 2,482,176
    const long SZ_XZ = (long)NB * 2 * DI * PT;    // 9,928,704
    const long SZ_DI = (long)NB * DI * PT;        // 4,964,352
    const long SZ_DBL = (long)NB * 44 * PT;       //   568,832
    float* xT     = ws + WTOT;
    float* resT   = xT + SZ_DM;
    float* hT     = resT + SZ_DM;
    float* xzT    = hT + SZ_DM;
    float* ucT    = xzT + SZ_XZ;
    float* dblT   = ucT + SZ_DI;
    float* deltaT = dblT + SZ_DBL;
    float* ygT    = deltaT + SZ_DI;
    float* vbuf   = ygT + SZ_DI;

    const unsigned short* probe = (const unsigned short*)d_in[5];  // norm_ws == ones

    SrcPtrs sp;
    for (int i = 0; i < 18; ++i) sp.p[i] = d_in[i];
    convert_kernel<<<dim3(64, 18), 256, 0, stream>>>(sp, probe, Wr);

    embed_kernel<<<dim3(7, DM, NB), 64, 0, stream>>>(Wr, xT);

    for (int i = 0; i < 4; ++i) {
        resnorm_kernel<<<dim3(7, NB), 256, 0, stream>>>(xT, resT, hT, Wr + O_NORMW + i * DM, i == 0);
        // in_proj: xz[b][n][t], N=768, K=192
        gemm_wt<0><<<dim3(4, 12, NB), 256, 0, stream>>>(
            hT, (long)DM * PT, Wr + O_INW + (long)i * DM * 2 * DI, nullptr,
            xzT, (long)2 * DI * PT, 2 * DI, DM);
        conv_silu_kernel<<<dim3(2, DI, NB), 256, 0, stream>>>(
            xzT, Wr + O_CONVW + i * DI * 4, Wr + O_CONVB + i * DI, ucT);
        // x_proj: dbl[b][n][t], N=44, K=384
        gemm_wt<0><<<dim3(4, 1, NB), 256, 0, stream>>>(
            ucT, (long)DI * PT, Wr + O_XPW + (long)i * DI * 44, nullptr,
            dblT, (long)44 * PT, 44, DI);
        // dt_proj + softplus: delta[b][d][t], N=384, K=12 (A = dblT rows 0..11)
        gemm_wt<1><<<dim3(4, 6, NB), 256, 0, stream>>>(
            dblT, (long)44 * PT, Wr + O_DTW + (long)i * 12 * DI, Wr + O_DTB + i * DI,
            deltaT, (long)DI * PT, DI, 12);
        scan_kernel<<<dim3(24, NB), 256, 0, stream>>>(
            deltaT, ucT, dblT, xzT, Wr + O_ALOG + (long)i * DI * DS, Wr + O_DS + i * DI, ygT);
        // out_proj: x[b][c][t], N=192, K=384
        gemm_wt<0><<<dim3(4, 3, NB), 256, 0, stream>>>(
            ygT, (long)DI * PT, Wr + O_OUTW + (long)i * DI * DM, nullptr,
            xT, (long)DM * PT, DM, DI);
    }

    finalnorm_kernel<<<NB, 256, 0, stream>>>(xT, resT, Wr + O_NORMF, vbuf);
    head_kernel<<<dim3(8, NB), 128, 0, stream>>>(vbuf, Wr + O_HEADW, Wr + O_HEADB, probe, (bf16*)d_out);
}

// Round 3
// 980.150 us; speedup vs baseline: 1.5861x; 1.5861x over previous
//
#include <hip/hip_runtime.h>
#include <hip/hip_bf16.h>
#include <hip/hip_fp16.h>

using bf16 = __hip_bfloat16;
typedef short short8 __attribute__((ext_vector_type(8)));
typedef float floatx4 __attribute__((ext_vector_type(4)));

#define LSEQ 401
#define NTOK 12832     // 32*401
#define NTOKP 12864    // padded to 201*64
#define DM 192
#define DI 384
#define NB 32

// ---- fp32 weights region layout (element offsets) ----
#define O_IMGS   0
#define O_PW     51200
#define O_PB     51968
#define O_CLS    52160
#define O_POS    52352
#define O_NORMW  129344
#define O_INW    130112
#define O_CONVW  719936
#define O_CONVB  726080
#define O_XPW    727616
#define O_DTW    795200
#define O_DTB    813632
#define O_ALOG   815168
#define O_DS     839744
#define O_OUTW   841280
#define O_NORMF  1136192
#define O_HEADW  1136384
#define O_HEADB  1328384
#define WTOT     1329408

// bf16 transposed-weight region (ushort element offsets within bfw)
#define BO_INWT  0         // 4 x [768][192]
#define BO_XPWT  589824    // 4 x [64][384] (rows 44..63 zero)
#define BO_OUTWT 688128    // 4 x [192][384]
#define BFTOT_F  491520    // total ushorts 983040 => floats 491520

__constant__ int g_sz[18] = {51200, 768, 192, 192, 76992, 768, 589824, 6144, 1536,
                             67584, 18432, 1536, 24576, 1536, 294912, 192, 192000, 1000};
__constant__ int g_off[18] = {O_IMGS, O_PW, O_PB, O_CLS, O_POS, O_NORMW, O_INW, O_CONVW,
                              O_CONVB, O_XPW, O_DTW, O_DTB, O_ALOG, O_DS, O_OUTW,
                              O_NORMF, O_HEADW, O_HEADB};

struct SrcPtrs { const void* p[18]; };

static __device__ __forceinline__ int probe_flag(const unsigned short* probe) {
    unsigned short u0 = probe[0];
    if (u0 == 0x3F80u) return 0;  // bf16 (1.0)
    if (u0 == 0x3C00u) return 2;  // fp16 (1.0)
    return 1;                     // fp32
}
static __device__ __forceinline__ float load_src(int flag, const void* p, long i) {
    if (flag == 0) return __bfloat162float(((const bf16*)p)[i]);
    if (flag == 2) return __half2float(((const __half*)p)[i]);
    return ((const float*)p)[i];
}
static __device__ __forceinline__ unsigned short f2b(float f) {
    bf16 h = __float2bfloat16(f);
    return *reinterpret_cast<unsigned short*>(&h);
}

// ---------------- ingest: fp32 copies of all inputs ----------------
__global__ void convert_kernel(SrcPtrs sp, const unsigned short* __restrict__ probe,
                               float* __restrict__ dst) {
    int flag = probe_flag(probe);
    int which = blockIdx.y;
    int n = g_sz[which];
    const void* src = sp.p[which];
    float* d = dst + g_off[which];
    for (int i = blockIdx.x * blockDim.x + threadIdx.x; i < n; i += gridDim.x * blockDim.x)
        d[i] = load_src(flag, src, i);
}

// ---------------- ingest: bf16 transposed GEMM weights [N][K] ----------------
__global__ void prep_wt_kernel(SrcPtrs sp, const unsigned short* __restrict__ probe,
                               unsigned short* __restrict__ bfw) {
    int flag = probe_flag(probe);
    int which = blockIdx.y, layer = blockIdx.z;
    int i = blockIdx.x * 256 + threadIdx.x;
    if (which == 0) {                       // in_w [192][768] -> [768][192]
        if (i >= 768 * 192) return;
        int n = i / 192, k = i % 192;
        float v = load_src(flag, sp.p[6], (long)layer * 147456 + (long)k * 768 + n);
        bfw[BO_INWT + (long)layer * 147456 + i] = f2b(v);
    } else if (which == 1) {                // xp_w [384][44] -> [64][384] zero-padded
        if (i >= 64 * 384) return;
        int n = i / 384, k = i % 384;
        float v = (n < 44) ? load_src(flag, sp.p[9], (long)layer * 16896 + (long)k * 44 + n) : 0.f;
        bfw[BO_XPWT + (long)layer * 24576 + i] = f2b(v);
    } else {                                // out_w [384][192] -> [192][384]
        if (i >= 192 * 384) return;
        int n = i / 384, k = i % 384;
        float v = load_src(flag, sp.p[14], (long)layer * 73728 + (long)k * 192 + n);
        bfw[BO_OUTWT + (long)layer * 73728 + i] = f2b(v);
    }
}

// ---------------- embed (token-major) ----------------
__global__ __launch_bounds__(192) void embed_kernel(const float* __restrict__ W, float* __restrict__ x) {
    const float* imgs = W + O_IMGS;
    const float* pw   = W + O_PW;
    const float* pb   = W + O_PB;
    const float* cls  = W + O_CLS;
    const float* pos  = W + O_POS;
    int tok = blockIdx.x;
    int b = tok / LSEQ, t = tok % LSEQ;
    int c = threadIdx.x;
    float v;
    if (t < 400) {
        float s0 = imgs[b * 1600 + t * 4 + 0];
        float s1 = imgs[b * 1600 + t * 4 + 1];
        float s2 = imgs[b * 1600 + t * 4 + 2];
        float s3 = imgs[b * 1600 + t * 4 + 3];
        v = s0 * pw[0 * DM + c] + s1 * pw[1 * DM + c] +
            s2 * pw[2 * DM + c] + s3 * pw[3 * DM + c] + pb[c] + pos[t * DM + c];
    } else {
        v = cls[c] + pos[400 * DM + c];
    }
    x[(long)tok * DM + c] = v;
}

// ---------------- residual + rmsnorm -> res fp32, h bf16 ----------------
__global__ __launch_bounds__(256) void resnorm_kernel(
    const float* __restrict__ x, float* __restrict__ res, unsigned short* __restrict__ hbf,
    const float* __restrict__ w, int first) {
    int wv = threadIdx.x >> 6, lane = threadIdx.x & 63;
    long tok = (long)blockIdx.x * 4 + wv;
    long base = tok * DM + lane * 4;
    float4 v = make_float4(0.f, 0.f, 0.f, 0.f);
    bool real = (tok < NTOK);
    if (real && lane < 48) {
        v = *(const float4*)(x + base);
        if (!first) {
            float4 r = *(const float4*)(res + base);
            v.x += r.x; v.y += r.y; v.z += r.z; v.w += r.w;
        }
        *(float4*)(res + base) = v;
    }
    float ss = v.x * v.x + v.y * v.y + v.z * v.z + v.w * v.w;
#pragma unroll
    for (int o = 1; o < 64; o <<= 1) ss += __shfl_xor(ss, o, 64);
    float inv = rsqrtf(ss * (1.f / DM) + 1e-5f);
    if (lane < 48) {
        if (real) {
            float4 w4 = *(const float4*)(w + lane * 4);
            ushort4 h;
            h.x = f2b(v.x * inv * w4.x); h.y = f2b(v.y * inv * w4.y);
            h.z = f2b(v.z * inv * w4.z); h.w = f2b(v.w * inv * w4.w);
            *(ushort4*)(hbf + base) = h;
        } else if (tok < NTOKP) {
            ushort4 h; h.x = h.y = h.z = h.w = 0;
            *(ushort4*)(hbf + base) = h;
        }
    }
}

// ---------------- MFMA GEMM: C[tok][n] = sum_k A[tok][k] * Worig[k][n] ----------------
// A bf16 [NTOKP][K], Wt bf16 [>=64*gridy][K] (row = out channel), C fp32 [NTOKP][NC]
__global__ __launch_bounds__(256) void gemm_mfma(
    const unsigned short* __restrict__ A, const unsigned short* __restrict__ Wt,
    float* __restrict__ C, int K, int N, int NC) {
    __shared__ unsigned short sA[64][72];
    __shared__ unsigned short sW[64][72];
    int tid = threadIdx.x;
    int w = tid >> 6, lane = tid & 63;
    int q = lane >> 4, m = lane & 15;
    long tok0 = (long)blockIdx.x * 64;
    int n0 = blockIdx.y * 64;
    floatx4 acc[4] = {};
    for (int k0 = 0; k0 < K; k0 += 64) {
        int slot = tid;
#pragma unroll
        for (int i = 0; i < 2; ++i, slot += 256) {
            int r = slot >> 3, c8 = (slot & 7) * 8;
            *(short8*)&sA[r][c8] = *(const short8*)(A + (tok0 + r) * K + k0 + c8);
            *(short8*)&sW[r][c8] = *(const short8*)(Wt + (long)(n0 + r) * K + k0 + c8);
        }
        __syncthreads();
#pragma unroll
        for (int q2 = 0; q2 < 64; q2 += 32) {
            short8 bfr = *(const short8*)&sA[w * 16 + m][q2 + q * 8];
#pragma unroll
            for (int nt = 0; nt < 4; ++nt) {
                short8 afr = *(const short8*)&sW[nt * 16 + m][q2 + q * 8];
                acc[nt] = __builtin_amdgcn_mfma_f32_16x16x32_bf16(afr, bfr, acc[nt], 0, 0, 0);
            }
        }
        __syncthreads();
    }
    long tok = tok0 + w * 16 + m;
#pragma unroll
    for (int nt = 0; nt < 4; ++nt) {
        int ch = n0 + nt * 16 + q * 4;
        float* dst = C + tok * NC + ch;
        if (ch + 3 < N) {
            *(float4*)dst = make_float4(acc[nt][0], acc[nt][1], acc[nt][2], acc[nt][3]);
        } else {
#pragma unroll
            for (int r = 0; r < 4; ++r)
                if (ch + r < N) dst[r] = acc[nt][r];
        }
    }
}

// ---------------- causal depthwise conv (width 4) + silu ----------------
__global__ __launch_bounds__(384) void conv_silu_kernel(
    const float* __restrict__ xz, const float* __restrict__ cw, const float* __restrict__ cb,
    float* __restrict__ ucf, unsigned short* __restrict__ ucb) {
    long tok = blockIdx.x;
    int d = threadIdx.x;
    int t = (int)(tok % LSEQ);
    float w0 = cw[d * 4 + 0], w1 = cw[d * 4 + 1], w2 = cw[d * 4 + 2], w3 = cw[d * 4 + 3];
    float acc = cb[d] + w3 * xz[tok * 768 + d];
    if (t >= 1) acc += w2 * xz[(tok - 1) * 768 + d];
    if (t >= 2) acc += w1 * xz[(tok - 2) * 768 + d];
    if (t >= 3) acc += w0 * xz[(tok - 3) * 768 + d];
    float sv = acc / (1.f + __expf(-acc));
    ucf[tok * DI + d] = sv;
    ucb[tok * DI + d] = f2b(sv);
}

// ---------------- dt_proj + softplus (K=12, VALU) ----------------
__global__ __launch_bounds__(384) void dtproj_kernel(
    const float* __restrict__ dbl, const float* __restrict__ dtw,
    const float* __restrict__ dtb, float* __restrict__ delta) {
    long tok = blockIdx.x;
    int d = threadIdx.x;
    __shared__ float sdt[12];
    if (d < 12) sdt[d] = dbl[tok * 44 + d];
    __syncthreads();
    float acc = dtb[d];
#pragma unroll
    for (int k = 0; k < 12; ++k) acc = fmaf(sdt[k], dtw[k * DI + d], acc);
    delta[tok * DI + d] = (acc > 20.f) ? acc : log1pf(__expf(acc));
}

// ---------------- selective scan (LDS-staged 64-t tiles); y may alias delta ----------------
__global__ __launch_bounds__(256) void scan_kernel(
    const float* __restrict__ delta, const float* __restrict__ ucf,
    const float* __restrict__ dbl, const float* __restrict__ Alog,
    const float* __restrict__ Dvec, float* __restrict__ y) {
    int b = blockIdx.y, dg = blockIdx.x;
    int d0 = dg * 16;
    int tid = threadIdx.x;
    int s = tid & 15, dl = tid >> 4;
    int d = d0 + dl;
    float a = -__expf(Alog[d * 16 + s]);
    float Dp = Dvec[d];
    long tokb = (long)b * LSEQ;
    __shared__ float sd[64][16], su[64][16], sB[64][16], sC[64][16];
    float h = 0.f;
    for (int t0 = 0; t0 < LSEQ; t0 += 64) {
        // stage (coalesced: 16 consecutive floats per 16-lane group)
        int r0 = tid >> 4, c = tid & 15;
#pragma unroll
        for (int i = 0; i < 4; ++i) {
            int r = r0 + i * 16;
            int t = t0 + r;
            bool ok = (t < LSEQ);
            long tok = tokb + t;
            sd[r][c] = ok ? delta[tok * DI + d0 + c] : 0.f;
            su[r][c] = ok ? ucf[tok * DI + d0 + c] : 0.f;
            sB[r][c] = ok ? dbl[tok * 44 + 12 + c] : 0.f;
            sC[r][c] = ok ? dbl[tok * 44 + 28 + c] : 0.f;
        }
        __syncthreads();
        int tmax = min(64, LSEQ - t0);
        for (int tt = 0; tt < tmax; ++tt) {
            float dlt = sd[tt][dl];
            float uu = su[tt][dl];
            float da = __expf(dlt * a);
            h = fmaf(da, h, dlt * uu * sB[tt][s]);
            float p = h * sC[tt][s];
            p += __shfl_xor(p, 1, 16);
            p += __shfl_xor(p, 2, 16);
            p += __shfl_xor(p, 4, 16);
            p += __shfl_xor(p, 8, 16);
            if (s == 0) y[(tokb + t0 + tt) * DI + d] = fmaf(uu, Dp, p);
        }
        __syncthreads();
    }
}

// ---------------- gate: ybf = bf16(y * silu(z)) ----------------
__global__ __launch_bounds__(384) void gate_kernel(
    const float* __restrict__ y, const float* __restrict__ xz,
    unsigned short* __restrict__ ybf) {
    long tok = blockIdx.x;
    int d = threadIdx.x;
    float z = xz[tok * 768 + DI + d];
    float v = y[tok * DI + d] * (z / (1.f + __expf(-z)));
    ybf[tok * DI + d] = f2b(v);
}

// ---------------- final norm at t=400 ----------------
__global__ __launch_bounds__(256) void finalnorm_kernel(
    const float* __restrict__ x, const float* __restrict__ res,
    const float* __restrict__ w, float* __restrict__ v) {
    int b = blockIdx.x;
    int c = threadIdx.x;
    long tok = (long)b * LSEQ + 400;
    __shared__ float sb[256];
    float val = 0.f;
    if (c < DM) val = x[tok * DM + c] + res[tok * DM + c];
    sb[c] = val * val;
    __syncthreads();
    for (int o = 128; o > 0; o >>= 1) {
        if (c < o) sb[c] += sb[c + o];
        __syncthreads();
    }
    float inv = rsqrtf(sb[0] * (1.f / DM) + 1e-5f);
    if (c < DM) v[b * DM + c] = val * inv * w[c];
}

// ---------------- head ----------------
__global__ __launch_bounds__(128) void head_kernel(
    const float* __restrict__ v, const float* __restrict__ hw, const float* __restrict__ hb,
    const unsigned short* __restrict__ probe, void* __restrict__ out) {
    int b = blockIdx.y;
    int n = blockIdx.x * 128 + threadIdx.x;
    __shared__ float vs[DM];
    for (int i = threadIdx.x; i < DM; i += 128) vs[i] = v[b * DM + i];
    __syncthreads();
    if (n < 1000) {
        float acc = hb[n];
#pragma unroll 4
        for (int c = 0; c < DM; ++c) acc = fmaf(vs[c], hw[c * 1000 + n], acc);
        int flag = probe_flag(probe);
        if (flag == 0)      ((bf16*)out)[b * 1000 + n] = (bf16)acc;
        else if (flag == 2) ((__half*)out)[b * 1000 + n] = __float2half(acc);
        else                ((float*)out)[b * 1000 + n] = acc;
    }
}

extern "C" void kernel_launch(void* const* d_in, const int* in_sizes, int n_in,
                              void* d_out, int out_size, void* d_ws, size_t ws_size,
                              hipStream_t stream) {
    float* ws = (float*)d_ws;
    float* Wr = ws;
    unsigned short* bfw = (unsigned short*)(ws + WTOT);
    float* act   = ws + WTOT + BFTOT_F;
    float* resT  = act;
    float* xB    = resT + (long)NTOKP * DM;
    float* xz    = xB + (long)NTOKP * DM;
    float* ucf   = xz + (long)NTOKP * 768;
    float* dbl   = ucf + (long)NTOKP * DI;
    float* delta = dbl + (long)NTOKP * 44;     // aliased as y (scan output)
    float* vbuf  = delta + (long)NTOKP * DI;
    unsigned short* hbf = (unsigned short*)(vbuf + NB * DM);
    unsigned short* ucb = hbf + (long)NTOKP * DM;   // aliased as ybf (gate output)

    const unsigned short* probe = (const unsigned short*)d_in[5];  // norm_ws == ones

    SrcPtrs sp;
    for (int i = 0; i < 18; ++i) sp.p[i] = d_in[i];
    convert_kernel<<<dim3(64, 18), 256, 0, stream>>>(sp, probe, Wr);
    prep_wt_kernel<<<dim3(576, 3, 4), 256, 0, stream>>>(sp, probe, bfw);

    embed_kernel<<<NTOK, 192, 0, stream>>>(Wr, xB);

    for (int i = 0; i < 4; ++i) {
        resnorm_kernel<<<NTOKP / 4, 256, 0, stream>>>(xB, resT, hbf, Wr + O_NORMW + i * DM, i == 0);
        // in_proj: xz[tok][768], K=192
        gemm_mfma<<<dim3(201, 12), 256, 0, stream>>>(
            hbf, bfw + BO_INWT + (long)i * 147456, xz, 192, 768, 768);
        conv_silu_kernel<<<NTOK, 384, 0, stream>>>(
            xz, Wr + O_CONVW + i * 1536, Wr + O_CONVB + i * DI, ucf, ucb);
        // x_proj: dbl[tok][44], K=384
        gemm_mfma<<<dim3(201, 1), 256, 0, stream>>>(
            ucb, bfw + BO_XPWT + (long)i * 24576, dbl, 384, 44, 44);
        dtproj_kernel<<<NTOK, 384, 0, stream>>>(
            dbl, Wr + O_DTW + i * 4608, Wr + O_DTB + i * DI, delta);
        scan_kernel<<<dim3(24, NB), 256, 0, stream>>>(
            delta, ucf, dbl, Wr + O_ALOG + i * 6144, Wr + O_DS + i * DI, delta);
        gate_kernel<<<NTOK, 384, 0, stream>>>(delta, xz, ucb);
        // out_proj: xB[tok][192], K=384
        gemm_mfma<<<dim3(201, 3), 256, 0, stream>>>(
            ucb, bfw + BO_OUTWT + (long)i * 73728, xB, 384, 192, 192);
    }

    finalnorm_kernel<<<NB, 256, 0, stream>>>(xB, resT, Wr + O_NORMF, vbuf);
    head_kernel<<<dim3(8, NB), 128, 0, stream>>>(vbuf, Wr + O_HEADW, Wr + O_HEADB, probe, d_out);
}

// Round 4
// 861.296 us; speedup vs baseline: 1.8050x; 1.1380x over previous
//
#include <hip/hip_runtime.h>
#include <hip/hip_bf16.h>
#include <hip/hip_fp16.h>

using bf16 = __hip_bfloat16;
typedef short short8 __attribute__((ext_vector_type(8)));
typedef float floatx4 __attribute__((ext_vector_type(4)));

#define LSEQ 401
#define NTOK 12832     // 32*401
#define NTOKP 12864    // padded to 201*64
#define DM 192
#define DI 384
#define NB 32

// ---- fp32 weights region layout (element offsets) ----
#define O_IMGS   0
#define O_PW     51200
#define O_PB     51968
#define O_CLS    52160
#define O_POS    52352
#define O_NORMW  129344
#define O_INW    130112
#define O_CONVW  719936
#define O_CONVB  726080
#define O_XPW    727616
#define O_DTW    795200
#define O_DTB    813632
#define O_ALOG   815168
#define O_DS     839744
#define O_OUTW   841280
#define O_NORMF  1136192
#define O_HEADW  1136384
#define O_HEADB  1328384
#define WTOT     1329408

// bf16 transposed-weight region (ushort element offsets within bfw)
#define BO_INWT  0         // 4 x [768][192]
#define BO_XPWT  589824    // 4 x [64][384] (rows 44..63 zero)
#define BO_OUTWT 688128    // 4 x [192][384]
#define BFTOT_F  491520    // total ushorts 983040 => floats 491520

__constant__ int g_sz[18] = {51200, 768, 192, 192, 76992, 768, 589824, 6144, 1536,
                             67584, 18432, 1536, 24576, 1536, 294912, 192, 192000, 1000};
__constant__ int g_off[18] = {O_IMGS, O_PW, O_PB, O_CLS, O_POS, O_NORMW, O_INW, O_CONVW,
                              O_CONVB, O_XPW, O_DTW, O_DTB, O_ALOG, O_DS, O_OUTW,
                              O_NORMF, O_HEADW, O_HEADB};

struct SrcPtrs { const void* p[18]; };

static __device__ __forceinline__ int probe_flag(const unsigned short* probe) {
    unsigned short u0 = probe[0];
    if (u0 == 0x3F80u) return 0;  // bf16 (1.0)
    if (u0 == 0x3C00u) return 2;  // fp16 (1.0)
    return 1;                     // fp32
}
static __device__ __forceinline__ float load_src(int flag, const void* p, long i) {
    if (flag == 0) return __bfloat162float(((const bf16*)p)[i]);
    if (flag == 2) return __half2float(((const __half*)p)[i]);
    return ((const float*)p)[i];
}
static __device__ __forceinline__ unsigned short f2b(float f) {
    bf16 h = __float2bfloat16(f);
    return *reinterpret_cast<unsigned short*>(&h);
}
static __device__ __forceinline__ float b2f_us(unsigned short us) {
    unsigned int ui = (unsigned int)us << 16;
    return __uint_as_float(ui);
}

// ---------------- ingest: fp32 copies of all inputs ----------------
__global__ void convert_kernel(SrcPtrs sp, const unsigned short* __restrict__ probe,
                               float* __restrict__ dst) {
    int flag = probe_flag(probe);
    int which = blockIdx.y;
    int n = g_sz[which];
    const void* src = sp.p[which];
    float* d = dst + g_off[which];
    for (int i = blockIdx.x * blockDim.x + threadIdx.x; i < n; i += gridDim.x * blockDim.x)
        d[i] = load_src(flag, src, i);
}

// ---------------- ingest: bf16 transposed GEMM weights [N][K] ----------------
__global__ void prep_wt_kernel(SrcPtrs sp, const unsigned short* __restrict__ probe,
                               unsigned short* __restrict__ bfw) {
    int flag = probe_flag(probe);
    int which = blockIdx.y, layer = blockIdx.z;
    int i = blockIdx.x * 256 + threadIdx.x;
    if (which == 0) {                       // in_w [192][768] -> [768][192]
        if (i >= 768 * 192) return;
        int n = i / 192, k = i % 192;
        float v = load_src(flag, sp.p[6], (long)layer * 147456 + (long)k * 768 + n);
        bfw[BO_INWT + (long)layer * 147456 + i] = f2b(v);
    } else if (which == 1) {                // xp_w [384][44] -> [64][384] zero-padded
        if (i >= 64 * 384) return;
        int n = i / 384, k = i % 384;
        float v = (n < 44) ? load_src(flag, sp.p[9], (long)layer * 16896 + (long)k * 44 + n) : 0.f;
        bfw[BO_XPWT + (long)layer * 24576 + i] = f2b(v);
    } else {                                // out_w [384][192] -> [192][384]
        if (i >= 192 * 384) return;
        int n = i / 384, k = i % 384;
        float v = load_src(flag, sp.p[14], (long)layer * 73728 + (long)k * 192 + n);
        bfw[BO_OUTWT + (long)layer * 73728 + i] = f2b(v);
    }
}

// ---------------- embed (token-major) ----------------
__global__ __launch_bounds__(192) void embed_kernel(const float* __restrict__ W, float* __restrict__ x) {
    const float* imgs = W + O_IMGS;
    const float* pw   = W + O_PW;
    const float* pb   = W + O_PB;
    const float* cls  = W + O_CLS;
    const float* pos  = W + O_POS;
    int tok = blockIdx.x;
    int b = tok / LSEQ, t = tok % LSEQ;
    int c = threadIdx.x;
    float v;
    if (t < 400) {
        float s0 = imgs[b * 1600 + t * 4 + 0];
        float s1 = imgs[b * 1600 + t * 4 + 1];
        float s2 = imgs[b * 1600 + t * 4 + 2];
        float s3 = imgs[b * 1600 + t * 4 + 3];
        v = s0 * pw[0 * DM + c] + s1 * pw[1 * DM + c] +
            s2 * pw[2 * DM + c] + s3 * pw[3 * DM + c] + pb[c] + pos[t * DM + c];
    } else {
        v = cls[c] + pos[400 * DM + c];
    }
    x[(long)tok * DM + c] = v;
}

// ---------------- residual + rmsnorm -> res fp32, h bf16 ----------------
__global__ __launch_bounds__(256) void resnorm_kernel(
    const float* __restrict__ x, float* __restrict__ res, unsigned short* __restrict__ hbf,
    const float* __restrict__ w, int first) {
    int wv = threadIdx.x >> 6, lane = threadIdx.x & 63;
    long tok = (long)blockIdx.x * 4 + wv;
    long base = tok * DM + lane * 4;
    float4 v = make_float4(0.f, 0.f, 0.f, 0.f);
    bool real = (tok < NTOK);
    if (real && lane < 48) {
        v = *(const float4*)(x + base);
        if (!first) {
            float4 r = *(const float4*)(res + base);
            v.x += r.x; v.y += r.y; v.z += r.z; v.w += r.w;
        }
        *(float4*)(res + base) = v;
    }
    float ss = v.x * v.x + v.y * v.y + v.z * v.z + v.w * v.w;
#pragma unroll
    for (int o = 1; o < 64; o <<= 1) ss += __shfl_xor(ss, o, 64);
    float inv = rsqrtf(ss * (1.f / DM) + 1e-5f);
    if (lane < 48) {
        if (real) {
            float4 w4 = *(const float4*)(w + lane * 4);
            ushort4 h;
            h.x = f2b(v.x * inv * w4.x); h.y = f2b(v.y * inv * w4.y);
            h.z = f2b(v.z * inv * w4.z); h.w = f2b(v.w * inv * w4.w);
            *(ushort4*)(hbf + base) = h;
        } else if (tok < NTOKP) {
            ushort4 h; h.x = h.y = h.z = h.w = 0;
            *(ushort4*)(hbf + base) = h;
        }
    }
}

// ---------------- MFMA GEMM: C[tok][n] = sum_k A[tok][k] * Worig[k][n] ----------------
__global__ __launch_bounds__(256) void gemm_mfma(
    const unsigned short* __restrict__ A, const unsigned short* __restrict__ Wt,
    float* __restrict__ C, int K, int N, int NC) {
    __shared__ unsigned short sA[64][72];
    __shared__ unsigned short sW[64][72];
    int tid = threadIdx.x;
    int w = tid >> 6, lane = tid & 63;
    int q = lane >> 4, m = lane & 15;
    long tok0 = (long)blockIdx.x * 64;
    int n0 = blockIdx.y * 64;
    floatx4 acc[4] = {};
    for (int k0 = 0; k0 < K; k0 += 64) {
        int slot = tid;
#pragma unroll
        for (int i = 0; i < 2; ++i, slot += 256) {
            int r = slot >> 3, c8 = (slot & 7) * 8;
            *(short8*)&sA[r][c8] = *(const short8*)(A + (tok0 + r) * K + k0 + c8);
            *(short8*)&sW[r][c8] = *(const short8*)(Wt + (long)(n0 + r) * K + k0 + c8);
        }
        __syncthreads();
#pragma unroll
        for (int q2 = 0; q2 < 64; q2 += 32) {
            short8 bfr = *(const short8*)&sA[w * 16 + m][q2 + q * 8];
#pragma unroll
            for (int nt = 0; nt < 4; ++nt) {
                short8 afr = *(const short8*)&sW[nt * 16 + m][q2 + q * 8];
                acc[nt] = __builtin_amdgcn_mfma_f32_16x16x32_bf16(afr, bfr, acc[nt], 0, 0, 0);
            }
        }
        __syncthreads();
    }
    long tok = tok0 + w * 16 + m;
#pragma unroll
    for (int nt = 0; nt < 4; ++nt) {
        int ch = n0 + nt * 16 + q * 4;
        float* dst = C + tok * NC + ch;
        if (ch + 3 < N) {
            *(float4*)dst = make_float4(acc[nt][0], acc[nt][1], acc[nt][2], acc[nt][3]);
        } else {
#pragma unroll
            for (int r = 0; r < 4; ++r)
                if (ch + r < N) dst[r] = acc[nt][r];
        }
    }
}

// ---------------- causal depthwise conv (width 4) + silu -> bf16 ----------------
__global__ __launch_bounds__(384) void conv_silu_kernel(
    const float* __restrict__ xz, const float* __restrict__ cw, const float* __restrict__ cb,
    unsigned short* __restrict__ ucb) {
    long tok = blockIdx.x;
    int d = threadIdx.x;
    int t = (int)(tok % LSEQ);
    float w0 = cw[d * 4 + 0], w1 = cw[d * 4 + 1], w2 = cw[d * 4 + 2], w3 = cw[d * 4 + 3];
    float acc = cb[d] + w3 * xz[tok * 768 + d];
    if (t >= 1) acc += w2 * xz[(tok - 1) * 768 + d];
    if (t >= 2) acc += w1 * xz[(tok - 2) * 768 + d];
    if (t >= 3) acc += w0 * xz[(tok - 3) * 768 + d];
    float sv = acc / (1.f + __expf(-acc));
    ucb[tok * DI + d] = f2b(sv);
}

// ---------------- fused dt_proj + selective scan + D + gate -> ybf bf16 ----------------
#define SPAD 68
__global__ __launch_bounds__(256) void scan_kernel(
    const float* __restrict__ dbl, const unsigned short* __restrict__ ucb,
    const float* __restrict__ xz, const float* __restrict__ dtw,
    const float* __restrict__ dtb, const float* __restrict__ Alog,
    const float* __restrict__ Dvec, unsigned short* __restrict__ ybf) {
    int dg = blockIdx.x, b = blockIdx.y;
    int d0 = dg * 16;
    long tokb = (long)b * LSEQ;
    int tid = threadIdx.x;
    int s = tid & 15, dl = tid >> 4;
    __shared__ float sdt[64][13];
    __shared__ float sB[16][SPAD], sC[16][SPAD], su[16][SPAD], sdelta[16][SPAD], sy[16][SPAD];
    __shared__ float sdtw[12][16], sdtb[16], sDp[16];
    if (tid < 192) sdtw[tid >> 4][tid & 15] = dtw[(tid >> 4) * DI + d0 + (tid & 15)];
    else if (tid < 208) sdtb[tid - 192] = dtb[d0 + (tid - 192)];
    else if (tid < 224) sDp[tid - 208] = Dvec[d0 + (tid - 208)];
    float a = -__expf(Alog[(d0 + dl) * 16 + s]);
    float h = 0.f;
    for (int t0 = 0; t0 < LSEQ; t0 += 64) {
        // ---- stage dt columns (64x12) ----
        for (int i = tid; i < 64 * 12; i += 256) {
            int r = i / 12, k = i % 12;
            int t = t0 + r;
            sdt[r][k] = (t < LSEQ) ? dbl[(long)(tokb + t) * 44 + k] : 0.f;
        }
        // ---- stage B, C, u in [ch/state][t] layout ----
        for (int i = tid; i < 1024; i += 256) {
            int c = i & 15, r = i >> 4;
            int t = t0 + r;
            bool ok = (t < LSEQ);
            long tok = tokb + t;
            sB[c][r] = ok ? dbl[tok * 44 + 12 + c] : 0.f;
            sC[c][r] = ok ? dbl[tok * 44 + 28 + c] : 0.f;
            su[c][r] = ok ? b2f_us(ucb[tok * DI + d0 + c]) : 0.f;
        }
        __syncthreads();
        // ---- dt_proj + softplus -> sdelta ----
        for (int i = tid; i < 1024; i += 256) {
            int c = i & 15, r = i >> 4;
            float acc = sdtb[c];
#pragma unroll
            for (int k = 0; k < 12; ++k) acc = fmaf(sdt[r][k], sdtw[k][c], acc);
            sdelta[c][r] = (acc > 20.f) ? acc : __logf(1.f + __expf(acc));
        }
        __syncthreads();
        // ---- serial scan: 8-t groups, h-chain is the only serial dependency ----
        for (int g = 0; g < 64; g += 8) {
            float dlt[8], uu[8], Bv[8], Cv[8];
            *(float4*)&dlt[0] = *(const float4*)&sdelta[dl][g];
            *(float4*)&dlt[4] = *(const float4*)&sdelta[dl][g + 4];
            *(float4*)&uu[0]  = *(const float4*)&su[dl][g];
            *(float4*)&uu[4]  = *(const float4*)&su[dl][g + 4];
            *(float4*)&Bv[0]  = *(const float4*)&sB[s][g];
            *(float4*)&Bv[4]  = *(const float4*)&sB[s][g + 4];
            *(float4*)&Cv[0]  = *(const float4*)&sC[s][g];
            *(float4*)&Cv[4]  = *(const float4*)&sC[s][g + 4];
            float da[8], dbu[8], p[8];
#pragma unroll
            for (int j = 0; j < 8; ++j) {
                da[j] = __expf(dlt[j] * a);
                dbu[j] = dlt[j] * uu[j] * Bv[j];
            }
#pragma unroll
            for (int j = 0; j < 8; ++j) {
                h = fmaf(da[j], h, dbu[j]);
                p[j] = h * Cv[j];
            }
#pragma unroll
            for (int j = 0; j < 8; ++j) {
                p[j] += __shfl_xor(p[j], 1, 16);
                p[j] += __shfl_xor(p[j], 2, 16);
                p[j] += __shfl_xor(p[j], 4, 16);
                p[j] += __shfl_xor(p[j], 8, 16);
            }
            if (s == 0) {
#pragma unroll
                for (int j = 0; j < 8; ++j) sy[dl][g + j] = p[j];
            }
        }
        __syncthreads();
        // ---- D-term + silu(z) gate + bf16 write ----
        for (int i = tid; i < 1024; i += 256) {
            int c = i & 15, r = i >> 4;
            int t = t0 + r;
            if (t < LSEQ) {
                long tok = tokb + t;
                float z = xz[tok * 768 + DI + d0 + c];
                float y = fmaf(su[c][r], sDp[c], sy[c][r]);
                float gz = z / (1.f + __expf(-z));
                ybf[tok * DI + d0 + c] = f2b(y * gz);
            }
        }
        __syncthreads();
    }
}

// ---------------- final norm at t=400 ----------------
__global__ __launch_bounds__(256) void finalnorm_kernel(
    const float* __restrict__ x, const float* __restrict__ res,
    const float* __restrict__ w, float* __restrict__ v) {
    int b = blockIdx.x;
    int c = threadIdx.x;
    long tok = (long)b * LSEQ + 400;
    __shared__ float sb[256];
    float val = 0.f;
    if (c < DM) val = x[tok * DM + c] + res[tok * DM + c];
    sb[c] = val * val;
    __syncthreads();
    for (int o = 128; o > 0; o >>= 1) {
        if (c < o) sb[c] += sb[c + o];
        __syncthreads();
    }
    float inv = rsqrtf(sb[0] * (1.f / DM) + 1e-5f);
    if (c < DM) v[b * DM + c] = val * inv * w[c];
}

// ---------------- head ----------------
__global__ __launch_bounds__(128) void head_kernel(
    const float* __restrict__ v, const float* __restrict__ hw, const float* __restrict__ hb,
    const unsigned short* __restrict__ probe, void* __restrict__ out) {
    int b = blockIdx.y;
    int n = blockIdx.x * 128 + threadIdx.x;
    __shared__ float vs[DM];
    for (int i = threadIdx.x; i < DM; i += 128) vs[i] = v[b * DM + i];
    __syncthreads();
    if (n < 1000) {
        float acc = hb[n];
#pragma unroll 4
        for (int c = 0; c < DM; ++c) acc = fmaf(vs[c], hw[c * 1000 + n], acc);
        int flag = probe_flag(probe);
        if (flag == 0)      ((bf16*)out)[b * 1000 + n] = (bf16)acc;
        else if (flag == 2) ((__half*)out)[b * 1000 + n] = __float2half(acc);
        else                ((float*)out)[b * 1000 + n] = acc;
    }
}

extern "C" void kernel_launch(void* const* d_in, const int* in_sizes, int n_in,
                              void* d_out, int out_size, void* d_ws, size_t ws_size,
                              hipStream_t stream) {
    float* ws = (float*)d_ws;
    float* Wr = ws;
    unsigned short* bfw = (unsigned short*)(ws + WTOT);
    float* act   = ws + WTOT + BFTOT_F;
    float* resT  = act;
    float* xB    = resT + (long)NTOKP * DM;
    float* xz    = xB + (long)NTOKP * DM;
    float* dbl   = xz + (long)NTOKP * 768;
    float* vbuf  = dbl + (long)NTOKP * 44;
    unsigned short* hbf = (unsigned short*)(vbuf + NB * DM);
    unsigned short* ucb = hbf + (long)NTOKP * DM;
    unsigned short* ybf = ucb + (long)NTOKP * DI;

    const unsigned short* probe = (const unsigned short*)d_in[5];  // norm_ws == ones

    SrcPtrs sp;
    for (int i = 0; i < 18; ++i) sp.p[i] = d_in[i];
    convert_kernel<<<dim3(64, 18), 256, 0, stream>>>(sp, probe, Wr);
    prep_wt_kernel<<<dim3(576, 3, 4), 256, 0, stream>>>(sp, probe, bfw);

    embed_kernel<<<NTOK, 192, 0, stream>>>(Wr, xB);

    for (int i = 0; i < 4; ++i) {
        resnorm_kernel<<<NTOKP / 4, 256, 0, stream>>>(xB, resT, hbf, Wr + O_NORMW + i * DM, i == 0);
        // in_proj: xz[tok][768], K=192
        gemm_mfma<<<dim3(201, 12), 256, 0, stream>>>(
            hbf, bfw + BO_INWT + (long)i * 147456, xz, 192, 768, 768);
        conv_silu_kernel<<<NTOK, 384, 0, stream>>>(
            xz, Wr + O_CONVW + i * 1536, Wr + O_CONVB + i * DI, ucb);
        // x_proj: dbl[tok][44], K=384
        gemm_mfma<<<dim3(201, 1), 256, 0, stream>>>(
            ucb, bfw + BO_XPWT + (long)i * 24576, dbl, 384, 44, 44);
        // fused dt_proj + scan + gate
        scan_kernel<<<dim3(24, NB), 256, 0, stream>>>(
            dbl, ucb, xz, Wr + O_DTW + i * 4608, Wr + O_DTB + i * DI,
            Wr + O_ALOG + i * 6144, Wr + O_DS + i * DI, ybf);
        // out_proj: xB[tok][192], K=384
        gemm_mfma<<<dim3(201, 3), 256, 0, stream>>>(
            ybf, bfw + BO_OUTWT + (long)i * 73728, xB, 384, 192, 192);
    }

    finalnorm_kernel<<<NB, 256, 0, stream>>>(xB, resT, Wr + O_NORMF, vbuf);
    head_kernel<<<dim3(8, NB), 128, 0, stream>>>(vbuf, Wr + O_HEADW, Wr + O_HEADB, probe, d_out);
}